// Round 2
// baseline (2587.058 us; speedup 1.0000x reference)
//
#include <hip/hip_runtime.h>
#include <hip/hip_bf16.h>

#define N_NODES 50000
#define N_EDGES 800000
#define HID     128
#define IMG_D   2048
#define TXT_D   768
#define NPB     8    // nodes per block in node_kernel
#define EPB     16   // edges per block in aggregate

// ---------------- feature GEMM: C[M,128] = A[M,K] @ B[K,128] ----------------
// 16 rows per block, A staged in LDS, each B element reused 16x in registers.
template<int K>
__global__ __launch_bounds__(128)
void feat_gemm(const float* __restrict__ A,
               const float* __restrict__ B,
               float* __restrict__ C, int M) {
    const int R = 16, KT = 64;
    __shared__ float sA[R][KT];
    int j = threadIdx.x;                 // 0..127 = output col
    int row0 = blockIdx.x * R;
    float acc[R];
    #pragma unroll
    for (int r = 0; r < R; ++r) acc[r] = 0.f;

    for (int k0 = 0; k0 < K; k0 += KT) {
        // stage A tile: R*KT = 1024 floats by 128 threads
        #pragma unroll
        for (int t = j; t < R * KT; t += 128) {
            int r = t >> 6, kk = t & 63;
            int row = row0 + r;
            sA[r][kk] = (row < M) ? A[(size_t)row * K + k0 + kk] : 0.f;
        }
        __syncthreads();
        for (int kk = 0; kk < KT; kk += 4) {
            float bv0 = B[(size_t)(k0 + kk + 0) * HID + j];
            float bv1 = B[(size_t)(k0 + kk + 1) * HID + j];
            float bv2 = B[(size_t)(k0 + kk + 2) * HID + j];
            float bv3 = B[(size_t)(k0 + kk + 3) * HID + j];
            #pragma unroll
            for (int r = 0; r < R; ++r) {
                const float4 av = *(const float4*)&sA[r][kk];
                acc[r] += av.x * bv0 + av.y * bv1 + av.z * bv2 + av.w * bv3;
            }
        }
        __syncthreads();
    }
    #pragma unroll
    for (int r = 0; r < R; ++r) {
        int row = row0 + r;
        if (row < M) C[(size_t)row * HID + j] = acc[r];
    }
}

// ---------------- block-wide reduce of NPB values (128 threads) ----------------
static __device__ __forceinline__ void block_reduce_vec(float v[NPB], float* tmp) {
    int lane = threadIdx.x & 63;
    int wave = threadIdx.x >> 6;
    #pragma unroll
    for (int off = 32; off > 0; off >>= 1) {
        #pragma unroll
        for (int n = 0; n < NPB; ++n) v[n] += __shfl_xor(v[n], off, 64);
    }
    if (lane == 0) {
        #pragma unroll
        for (int n = 0; n < NPB; ++n) tmp[wave * NPB + n] = v[n];
    }
    __syncthreads();
    #pragma unroll
    for (int n = 0; n < NPB; ++n) v[n] = tmp[n] + tmp[NPB + n];
    __syncthreads();
}

// ---------------- gate MLP for NPB nodes at once ----------------
static __device__ __forceinline__ void gate_mlp_multi(
        const float (*sx)[2 * HID], float (*sh)[HID], float* tmp,
        const float* __restrict__ W1, const float* __restrict__ b1,
        const float* __restrict__ W2, const float* __restrict__ b2,
        const float* __restrict__ W3, const float* __restrict__ b3,
        float g[NPB]) {
    int j = threadIdx.x;
    float acc[NPB];
    float bb = b1[j];
    #pragma unroll
    for (int n = 0; n < NPB; ++n) acc[n] = bb;
    for (int i = 0; i < 2 * HID; i += 4) {
        float w0 = W1[(size_t)(i + 0) * HID + j];
        float w1 = W1[(size_t)(i + 1) * HID + j];
        float w2 = W1[(size_t)(i + 2) * HID + j];
        float w3 = W1[(size_t)(i + 3) * HID + j];
        #pragma unroll
        for (int n = 0; n < NPB; ++n) {
            const float4 xv = *(const float4*)&sx[n][i];
            acc[n] += xv.x * w0 + xv.y * w1 + xv.z * w2 + xv.w * w3;
        }
    }
    #pragma unroll
    for (int n = 0; n < NPB; ++n) sh[n][j] = fmaxf(acc[n], 0.f);
    __syncthreads();

    bb = b2[j];
    #pragma unroll
    for (int n = 0; n < NPB; ++n) acc[n] = bb;
    for (int i = 0; i < HID; i += 4) {
        float w0 = W2[(size_t)(i + 0) * HID + j];
        float w1 = W2[(size_t)(i + 1) * HID + j];
        float w2 = W2[(size_t)(i + 2) * HID + j];
        float w3 = W2[(size_t)(i + 3) * HID + j];
        #pragma unroll
        for (int n = 0; n < NPB; ++n) {
            const float4 xv = *(const float4*)&sh[n][i];
            acc[n] += xv.x * w0 + xv.y * w1 + xv.z * w2 + xv.w * w3;
        }
    }
    float w3v = W3[j], b3v = b3[0];
    #pragma unroll
    for (int n = 0; n < NPB; ++n) acc[n] = fmaxf(acc[n], 0.f) * w3v;
    block_reduce_vec(acc, tmp);
    #pragma unroll
    for (int n = 0; n < NPB; ++n) g[n] = 1.f / (1.f + expf(-(acc[n] + b3v)));
}

// ---------------- per-node fused kernel (NPB nodes / block) ----------------
__global__ __launch_bounds__(128)
void node_kernel(const int* __restrict__ node_id,
                 const float* __restrict__ emb_table,
                 const float* __restrict__ img_f_all,
                 const float* __restrict__ txt_f_all,
                 const float* __restrict__ iW1, const float* __restrict__ ib1,
                 const float* __restrict__ iW2, const float* __restrict__ ib2,
                 const float* __restrict__ iW3, const float* __restrict__ ib3,
                 const float* __restrict__ tW1, const float* __restrict__ tb1,
                 const float* __restrict__ tW2, const float* __restrict__ tb2,
                 const float* __restrict__ tW3, const float* __restrict__ tb3,
                 const float* __restrict__ combW, const float* __restrict__ combb,
                 const float* __restrict__ fcW, const float* __restrict__ attn,
                 float* __restrict__ z_out, float* __restrict__ e_src, float* __restrict__ e_dst) {
    __shared__ float sx[NPB][2 * HID];   // 8 KB
    __shared__ float sh[NPB][HID];       // 4 KB
    __shared__ float tmp[2 * NPB];
    int j = threadIdx.x;
    int n0 = blockIdx.x * NPB;

    float embed[NPB], imgf[NPB], txtf[NPB];
    #pragma unroll
    for (int n = 0; n < NPB; ++n) {
        int node = n0 + n;
        int nid = node_id[node];
        embed[n] = emb_table[(size_t)nid * HID + j];
        imgf[n]  = img_f_all[(size_t)node * HID + j];
        txtf[n]  = txt_f_all[(size_t)node * HID + j];
    }

    // ---- image gate ----
    #pragma unroll
    for (int n = 0; n < NPB; ++n) { sx[n][j] = embed[n]; sx[n][HID + j] = imgf[n]; }
    __syncthreads();
    float g[NPB];
    gate_mlp_multi(sx, sh, tmp, iW1, ib1, iW2, ib2, iW3, ib3, g);
    float img_v[NPB];
    #pragma unroll
    for (int n = 0; n < NPB; ++n) img_v[n] = g[n] * imgf[n] + (1.f - g[n]) * embed[n];

    // ---- text gate ----  (gate_mlp_multi ends with a barrier; sx rewrite safe)
    #pragma unroll
    for (int n = 0; n < NPB; ++n) { sx[n][j] = embed[n]; sx[n][HID + j] = txtf[n]; }
    __syncthreads();
    gate_mlp_multi(sx, sh, tmp, tW1, tb1, tW2, tb2, tW3, tb3, g);
    float txt_v[NPB];
    #pragma unroll
    for (int n = 0; n < NPB; ++n) txt_v[n] = g[n] * txtf[n] + (1.f - g[n]) * embed[n];

    // ---- combine (linear gate, no sigmoid) ----
    #pragma unroll
    for (int n = 0; n < NPB; ++n) { sx[n][j] = img_v[n]; sx[n][HID + j] = txt_v[n]; }
    __syncthreads();
    float acc[NPB];
    float bb = combb[j];
    #pragma unroll
    for (int n = 0; n < NPB; ++n) acc[n] = bb;
    for (int i = 0; i < 2 * HID; i += 4) {
        float w0 = combW[(size_t)(i + 0) * HID + j];
        float w1 = combW[(size_t)(i + 1) * HID + j];
        float w2 = combW[(size_t)(i + 2) * HID + j];
        float w3 = combW[(size_t)(i + 3) * HID + j];
        #pragma unroll
        for (int n = 0; n < NPB; ++n) {
            const float4 xv = *(const float4*)&sx[n][i];
            acc[n] += xv.x * w0 + xv.y * w1 + xv.z * w2 + xv.w * w3;
        }
    }
    float hcur[NPB];
    #pragma unroll
    for (int n = 0; n < NPB; ++n) hcur[n] = acc[n] * img_v[n] + (1.f - acc[n]) * txt_v[n];
    __syncthreads();
    #pragma unroll
    for (int n = 0; n < NPB; ++n) sh[n][j] = hcur[n];
    __syncthreads();

    // ---- fc: z = h @ fc_W ----
    #pragma unroll
    for (int n = 0; n < NPB; ++n) acc[n] = 0.f;
    for (int i = 0; i < HID; i += 4) {
        float w0 = fcW[(size_t)(i + 0) * HID + j];
        float w1 = fcW[(size_t)(i + 1) * HID + j];
        float w2 = fcW[(size_t)(i + 2) * HID + j];
        float w3 = fcW[(size_t)(i + 3) * HID + j];
        #pragma unroll
        for (int n = 0; n < NPB; ++n) {
            const float4 xv = *(const float4*)&sh[n][i];
            acc[n] += xv.x * w0 + xv.y * w1 + xv.z * w2 + xv.w * w3;
        }
    }
    #pragma unroll
    for (int n = 0; n < NPB; ++n)
        z_out[(size_t)(n0 + n) * HID + j] = acc[n];

    // ---- e_src / e_dst ----
    float a1 = attn[j], a2 = attn[HID + j];
    float v1[NPB], v2[NPB];
    #pragma unroll
    for (int n = 0; n < NPB; ++n) { v1[n] = acc[n] * a1; v2[n] = acc[n] * a2; }
    block_reduce_vec(v1, tmp);
    block_reduce_vec(v2, tmp);
    if (j == 0) {
        #pragma unroll
        for (int n = 0; n < NPB; ++n) { e_src[n0 + n] = v1[n]; e_dst[n0 + n] = v2[n]; }
    }
}

// ---------------- edge phase 1: exp(e) + denom ----------------
__global__ __launch_bounds__(256)
void edge_softmax_pre(const int* __restrict__ src, const int* __restrict__ dst,
                      const float* __restrict__ e_src, const float* __restrict__ e_dst,
                      float* __restrict__ exbuf, float* __restrict__ denom) {
    int k = blockIdx.x * 256 + threadIdx.x;
    if (k >= N_EDGES) return;
    float e = e_src[src[k]] + e_dst[dst[k]];
    e = (e >= 0.f) ? e : 0.01f * e;   // leaky_relu(0.01)
    // softmax is shift-invariant: skip segment_max; e is O(0.1) so exp is safe
    float ex = expf(e);
    exbuf[k] = ex;
    atomicAdd(&denom[dst[k]], ex);
}

// ---------------- edge phase 2: weighted aggregation into d_out (f32) ----------------
__global__ __launch_bounds__(128)
void edge_aggregate(const int* __restrict__ src, const int* __restrict__ dst,
                    const float* __restrict__ exbuf, const float* __restrict__ denom,
                    const float* __restrict__ z, float* __restrict__ hout) {
    int j = threadIdx.x;
    int base = blockIdx.x * EPB;
    int end = base + EPB;
    if (end > N_EDGES) end = N_EDGES;
    for (int k = base; k < end; ++k) {
        int d = dst[k], s = src[k];
        float alpha = exbuf[k] / fmaxf(denom[d], 1e-20f);
        atomicAdd(&hout[(size_t)d * HID + j], alpha * z[(size_t)s * HID + j]);
    }
}

extern "C" void kernel_launch(void* const* d_in, const int* in_sizes, int n_in,
                              void* d_out, int out_size, void* d_ws, size_t ws_size,
                              hipStream_t stream) {
    const int*   node_id = (const int*)d_in[0];
    const float* img_h   = (const float*)d_in[1];
    const float* txt_h   = (const float*)d_in[2];
    const int*   src     = (const int*)d_in[3];
    const int*   dst     = (const int*)d_in[4];
    const float* emb     = (const float*)d_in[5];
    const float* W_img   = (const float*)d_in[6];
    const float* iW1     = (const float*)d_in[7];
    const float* ib1     = (const float*)d_in[8];
    const float* iW2     = (const float*)d_in[9];
    const float* ib2     = (const float*)d_in[10];
    const float* iW3     = (const float*)d_in[11];
    const float* ib3     = (const float*)d_in[12];
    const float* W_txt   = (const float*)d_in[13];
    const float* tW1     = (const float*)d_in[14];
    const float* tb1     = (const float*)d_in[15];
    const float* tW2     = (const float*)d_in[16];
    const float* tb2     = (const float*)d_in[17];
    const float* tW3     = (const float*)d_in[18];
    const float* tb3     = (const float*)d_in[19];
    const float* combW   = (const float*)d_in[20];
    const float* combb   = (const float*)d_in[21];
    const float* fcW     = (const float*)d_in[22];
    const float* attn    = (const float*)d_in[23];

    float* ws    = (float*)d_ws;
    float* img_f = ws;                                  // N*HID  (z aliases this)
    float* txt_f = img_f + (size_t)N_NODES * HID;       // N*HID
    float* e_s   = txt_f + (size_t)N_NODES * HID;       // N
    float* e_d   = e_s + N_NODES;                       // N
    float* denom = e_d + N_NODES;                       // N
    float* exbuf = denom + N_NODES;                     // E
    float* z     = img_f;  // safe: node_kernel reads img_f[n] before writing z[n] in-thread

    float* out_f = (float*)d_out;
    hipMemsetAsync(denom, 0, (size_t)N_NODES * sizeof(float), stream);
    hipMemsetAsync(out_f, 0, (size_t)N_NODES * HID * sizeof(float), stream);

    feat_gemm<IMG_D><<<(N_NODES + 15) / 16, 128, 0, stream>>>(img_h, W_img, img_f, N_NODES);
    feat_gemm<TXT_D><<<(N_NODES + 15) / 16, 128, 0, stream>>>(txt_h, W_txt, txt_f, N_NODES);

    node_kernel<<<N_NODES / NPB, 128, 0, stream>>>(node_id, emb, img_f, txt_f,
        iW1, ib1, iW2, ib2, iW3, ib3,
        tW1, tb1, tW2, tb2, tW3, tb3,
        combW, combb, fcW, attn, z, e_s, e_d);

    edge_softmax_pre<<<(N_EDGES + 255) / 256, 256, 0, stream>>>(src, dst, e_s, e_d, exbuf, denom);

    edge_aggregate<<<(N_EDGES + EPB - 1) / EPB, 128, 0, stream>>>(src, dst, exbuf, denom, z, out_f);
}